// Round 1
// baseline (143.935 us; speedup 1.0000x reference)
//
#include <hip/hip_runtime.h>
#include <hip/hip_bf16.h>

// out[b,o] = sum_i x[b,i]*w[o,i] + bias[o]; M=4096 (batch), N=2048 (out), K=2048 (in)
// Strategy: fp32 -> bf16 convert into d_ws, then m97-style MFMA GEMM
// (128x128 tile, BK=32, global_load_lds width=16, 16x16x32 bf16 MFMA, fp32 acc).

#define M_DIM 4096
#define N_DIM 2048
#define K_DIM 2048
#define BK 32

typedef unsigned short ushort_t;
typedef __attribute__((ext_vector_type(8))) short short8;          // 8 bf16 = 4 VGPRs (A/B frag)
typedef __attribute__((ext_vector_type(4))) float float4v;         // C/D frag
typedef __attribute__((ext_vector_type(8))) unsigned short ushort8;

// ---------------- fp32 -> bf16 (RNE) conversion ----------------
__device__ __forceinline__ unsigned short f2bf_rne(float f) {
    unsigned int u = __builtin_bit_cast(unsigned int, f);
    u += 0x7FFFu + ((u >> 16) & 1u);
    return (unsigned short)(u >> 16);
}

__global__ void __launch_bounds__(256) cvt_f32_to_bf16(const float* __restrict__ in,
                                                       ushort8* __restrict__ out, int n8) {
    int idx = blockIdx.x * 256 + threadIdx.x;
    if (idx >= n8) return;
    const float4v* in4 = (const float4v*)in;
    float4v a = in4[idx * 2];
    float4v b = in4[idx * 2 + 1];
    ushort8 r;
    r[0] = f2bf_rne(a[0]); r[1] = f2bf_rne(a[1]);
    r[2] = f2bf_rne(a[2]); r[3] = f2bf_rne(a[3]);
    r[4] = f2bf_rne(b[0]); r[5] = f2bf_rne(b[1]);
    r[6] = f2bf_rne(b[2]); r[7] = f2bf_rne(b[3]);
    out[idx] = r;
}

// ---------------- async global -> LDS (16B per lane) ----------------
// NOTE: LDS dest is wave-uniform base; HW scatters lane L to base + L*16.
__device__ __forceinline__ void async_load16(const void* g, void* l) {
    __builtin_amdgcn_global_load_lds(
        (const __attribute__((address_space(1))) void*)(g),
        (__attribute__((address_space(3))) void*)(l), 16, 0, 0);
}

// ---------------- bf16 MFMA GEMM, C = Xb * Wb^T + bias ----------------
// Xb: [M,K] bf16 row-major, Wb: [N,K] bf16 row-major (B^T layout).
__global__ void __launch_bounds__(256) gemm_bf16(const ushort_t* __restrict__ xb,
                                                 const ushort_t* __restrict__ wb,
                                                 const float* __restrict__ bias,
                                                 float* __restrict__ out) {
    __shared__ ushort_t ldsA[128 * BK];   // 8 KB
    __shared__ ushort_t ldsB[128 * BK];   // 8 KB

    const int tid  = threadIdx.x;
    const int wave = tid >> 6;
    const int lane = tid & 63;
    const int quad = lane >> 4;    // 0..3
    const int lrow = lane & 15;    // 0..15

    const int bm = blockIdx.x >> 4;    // 0..31 (M/128)
    const int bn = blockIdx.x & 15;    // 0..15 (N/128)
    const int rowBase = bm * 128;
    const int colBase = bn * 128;

    const int waveR = (wave >> 1) * 64;   // wave row offset in tile
    const int waveC = (wave & 1) * 64;    // wave col offset in tile

    // Staging: each wave copies 32 rows (2 instrs x 16 rows) of A and B tiles.
    // One global_load_lds: lane L -> row (L>>2), 16B chunk (L&3). Rows are 64B.
    const int srow = wave * 32 + (lane >> 2);     // 16-row group handled by instr 0
    const int scol = (lane & 3) * 8;              // ushort offset within row
    const ushort_t* gA0 = xb + (long long)(rowBase + srow) * K_DIM + scol;
    const ushort_t* gA1 = gA0 + (long long)16 * K_DIM;
    const ushort_t* gB0 = wb + (long long)(colBase + srow) * K_DIM + scol;
    const ushort_t* gB1 = gB0 + (long long)16 * K_DIM;
    ushort_t* lA0 = &ldsA[(wave * 32) * BK];       // wave-uniform LDS bases
    ushort_t* lA1 = &ldsA[(wave * 32 + 16) * BK];
    ushort_t* lB0 = &ldsB[(wave * 32) * BK];
    ushort_t* lB1 = &ldsB[(wave * 32 + 16) * BK];

    float4v acc[4][4] = {};

    for (int k0 = 0; k0 < K_DIM; k0 += BK) {
        async_load16(gA0, lA0);
        async_load16(gA1, lA1);
        async_load16(gB0, lB0);
        async_load16(gB1, lB1);
        gA0 += BK; gA1 += BK; gB0 += BK; gB1 += BK;
        __syncthreads();   // drains vmcnt before barrier

        short8 afrag[4], bfrag[4];
#pragma unroll
        for (int i = 0; i < 4; i++) {
            // A-frag: A[m=lane&15][k=quad*8+j]; B-frag: B[k=quad*8+j][n=lane&15]
            afrag[i] = *(const short8*)&ldsA[(waveR + i * 16 + lrow) * BK + quad * 8];
            bfrag[i] = *(const short8*)&ldsB[(waveC + i * 16 + lrow) * BK + quad * 8];
        }
#pragma unroll
        for (int mi = 0; mi < 4; mi++)
#pragma unroll
            for (int ni = 0; ni < 4; ni++)
                acc[mi][ni] = __builtin_amdgcn_mfma_f32_16x16x32_bf16(
                    afrag[mi], bfrag[ni], acc[mi][ni], 0, 0, 0);
        __syncthreads();
    }

    // Epilogue: C/D layout col=lane&15, row=quad*4+reg
#pragma unroll
    for (int ni = 0; ni < 4; ni++) {
        const int col = colBase + waveC + ni * 16 + lrow;
        const float bv = bias[col];
#pragma unroll
        for (int mi = 0; mi < 4; mi++) {
            const int row0 = rowBase + waveR + mi * 16 + quad * 4;
            float4v v = acc[mi][ni];
#pragma unroll
            for (int i = 0; i < 4; i++)
                out[(long long)(row0 + i) * N_DIM + col] = v[i] + bv;
        }
    }
}

// ---------------- fallback (ws too small): fp32 naive ----------------
__global__ void __launch_bounds__(256) linear_naive(const float* __restrict__ x,
                                                    const float* __restrict__ w,
                                                    const float* __restrict__ bias,
                                                    float* __restrict__ out) {
    __shared__ float xs[K_DIM];
    const int b = blockIdx.y;
    const int o = blockIdx.x * 256 + threadIdx.x;
    for (int k = threadIdx.x; k < K_DIM; k += 256)
        xs[k] = x[(long long)b * K_DIM + k];
    __syncthreads();
    const float4v* wr = (const float4v*)(w + (long long)o * K_DIM);
    float s = 0.f;
    for (int k4 = 0; k4 < K_DIM / 4; k4++) {
        float4v wv = wr[k4];
        float4v xv = *(const float4v*)&xs[k4 * 4];
        s += xv[0] * wv[0] + xv[1] * wv[1] + xv[2] * wv[2] + xv[3] * wv[3];
    }
    out[(long long)b * N_DIM + o] = s + bias[o];
}

extern "C" void kernel_launch(void* const* d_in, const int* in_sizes, int n_in,
                              void* d_out, int out_size, void* d_ws, size_t ws_size,
                              hipStream_t stream) {
    const float* x    = (const float*)d_in[0];   // [4096, 2048]
    const float* w    = (const float*)d_in[1];   // [2048, 2048]
    const float* bias = (const float*)d_in[2];   // [2048]
    float* out = (float*)d_out;                  // [4096, 2048]

    const size_t xElems = (size_t)M_DIM * K_DIM;   // 8388608
    const size_t wElems = (size_t)N_DIM * K_DIM;   // 4194304
    const size_t need = (xElems + wElems) * sizeof(ushort_t);  // ~25.2 MB

    if (ws_size >= need) {
        ushort_t* xb = (ushort_t*)d_ws;
        ushort_t* wb = xb + xElems;
        cvt_f32_to_bf16<<<(int)(xElems / 8 / 256), 256, 0, stream>>>(x, (ushort8*)xb, (int)(xElems / 8));
        cvt_f32_to_bf16<<<(int)(wElems / 8 / 256), 256, 0, stream>>>(w, (ushort8*)wb, (int)(wElems / 8));
        gemm_bf16<<<(M_DIM / 128) * (N_DIM / 128), 256, 0, stream>>>(xb, wb, bias, out);
    } else {
        dim3 grid(N_DIM / 256, M_DIM);
        linear_naive<<<grid, 256, 0, stream>>>(x, w, bias, out);
    }
}

// Round 2
// 138.998 us; speedup vs baseline: 1.0355x; 1.0355x over previous
//
#include <hip/hip_runtime.h>
#include <hip/hip_bf16.h>

// out[b,o] = sum_i x[b,i]*w[o,i] + bias[o]; M=4096, N=2048, K=2048, fp32 io.
// R2: fused fp32->bf16 cvt (one launch), then MFMA GEMM with
//  - 512-thread blocks (8 waves, 2x4 wave grid, 64x32 wave-tiles) to double
//    resident waves/CU (grid is 512 blocks = 2/CU, was occupancy-capped)
//  - XOR-swizzled LDS chunk placement: row r's 16B chunk q stored at
//    position q ^ ((r>>1)&3). global_load_lds lane->LDS map is fixed
//    (base + lane*16), so the swizzle is applied on the GLOBAL side of the
//    staging load; reads then spread evenly over all 8 bank slots -> no
//    LDS bank conflicts (was 4.19M extra cycles/dispatch, ~8-way).

#define M_DIM 4096
#define N_DIM 2048
#define K_DIM 2048
#define BK 32

typedef unsigned short ushort_t;
typedef __attribute__((ext_vector_type(8))) short short8;      // 8 bf16 (A/B frag)
typedef __attribute__((ext_vector_type(4))) float float4v;     // C/D frag
typedef __attribute__((ext_vector_type(8))) unsigned short ushort8;

// ---------------- fp32 -> bf16 (RNE), x and w fused in one launch ----------------
__device__ __forceinline__ unsigned short f2bf_rne(float f) {
    unsigned int u = __builtin_bit_cast(unsigned int, f);
    u += 0x7FFFu + ((u >> 16) & 1u);
    return (unsigned short)(u >> 16);
}

__global__ void __launch_bounds__(256) cvt_both(const float* __restrict__ x,
                                                const float* __restrict__ w,
                                                ushort8* __restrict__ ws8,
                                                int xN8, int totN8) {
    int idx = blockIdx.x * 256 + threadIdx.x;
    if (idx >= totN8) return;
    const float4v* in4 = (idx < xN8) ? (const float4v*)x + (size_t)idx * 2
                                     : (const float4v*)w + (size_t)(idx - xN8) * 2;
    float4v a = in4[0];
    float4v b = in4[1];
    ushort8 r;
    r[0] = f2bf_rne(a[0]); r[1] = f2bf_rne(a[1]);
    r[2] = f2bf_rne(a[2]); r[3] = f2bf_rne(a[3]);
    r[4] = f2bf_rne(b[0]); r[5] = f2bf_rne(b[1]);
    r[6] = f2bf_rne(b[2]); r[7] = f2bf_rne(b[3]);
    ws8[idx] = r;
}

// ---------------- async global -> LDS (16B per lane; dest = base + lane*16) ----
__device__ __forceinline__ void async_load16(const void* g, void* l) {
    __builtin_amdgcn_global_load_lds(
        (const __attribute__((address_space(1))) void*)(g),
        (__attribute__((address_space(3))) void*)(l), 16, 0, 0);
}

// ---------------- bf16 MFMA GEMM, C = Xb * Wb^T + bias ----------------
// Xb: [M,K] bf16 row-major, Wb: [N,K] bf16 row-major.
// Block: 128x128 tile, 512 threads = 8 waves in 2(row) x 4(col); wave-tile 64x32.
__global__ void __launch_bounds__(512) gemm_bf16(const ushort_t* __restrict__ xb,
                                                 const ushort_t* __restrict__ wb,
                                                 const float* __restrict__ bias,
                                                 float* __restrict__ out) {
    __shared__ ushort_t ldsA[128 * BK];   // 8 KB
    __shared__ ushort_t ldsB[128 * BK];   // 8 KB

    const int tid  = threadIdx.x;
    const int wave = tid >> 6;
    const int lane = tid & 63;
    const int quad = lane >> 4;    // 0..3
    const int lrow = lane & 15;    // 0..15

    const int bm = blockIdx.x >> 4;    // 0..31
    const int bn = blockIdx.x & 15;    // 0..15
    const int rowBase = bm * 128;
    const int colBase = bn * 128;

    const int waveR = (wave >> 2) * 64;   // 0 or 64
    const int waveC = (wave & 3) * 32;    // 0,32,64,96

    // ---- staging: waves 0-3 stage A (rows sgrp*32..+32), waves 4-7 stage B ----
    // One instr covers 16 rows: lane L -> LDS slot L (16B each).
    // Swizzle: the chunk stored at position p of row r is q = p ^ ((r>>1)&3);
    // with r_local = L>>2, p = L&3 -> q = (L&3) ^ ((L>>3)&3).
    const int  sgrp = wave & 3;
    const bool isB  = wave >= 4;
    const int  R0   = sgrp * 32;
    const int  q    = (lane & 3) ^ ((lane >> 3) & 3);
    const ushort_t* src = isB ? wb + (long long)colBase * K_DIM
                              : xb + (long long)rowBase * K_DIM;
    const ushort_t* g0 = src + (long long)(R0 + (lane >> 2)) * K_DIM + q * 8;
    const ushort_t* g1 = g0 + (long long)16 * K_DIM;
    ushort_t* lbase = (isB ? ldsB : ldsA) + R0 * BK;  // wave-uniform
    ushort_t* l0 = lbase;
    ushort_t* l1 = lbase + 16 * BK;

    // ---- fragment read pointers (swizzle term is lane-constant) ----
    // Read row r, k-chunk `quad` at ushort offset r*BK + (quad ^ ((r>>1)&3))*8;
    // r = waveR/C + mi*16 + lrow, and (r>>1)&3 == (lrow>>1)&3 (offsets are x16).
    const int sw = (quad ^ ((lrow >> 1) & 3)) * 8;
    const ushort_t* aP = &ldsA[(waveR + lrow) * BK + sw];
    const ushort_t* bP = &ldsB[(waveC + lrow) * BK + sw];

    float4v acc[4][2] = {};

    for (int k0 = 0; k0 < K_DIM; k0 += BK) {
        async_load16(g0, l0);
        async_load16(g1, l1);
        g0 += BK; g1 += BK;
        __syncthreads();

        short8 af[4], bf[2];
#pragma unroll
        for (int mi = 0; mi < 4; mi++)
            af[mi] = *(const short8*)(aP + mi * 16 * BK);
#pragma unroll
        for (int ni = 0; ni < 2; ni++)
            bf[ni] = *(const short8*)(bP + ni * 16 * BK);
#pragma unroll
        for (int mi = 0; mi < 4; mi++)
#pragma unroll
            for (int ni = 0; ni < 2; ni++)
                acc[mi][ni] = __builtin_amdgcn_mfma_f32_16x16x32_bf16(
                    af[mi], bf[ni], acc[mi][ni], 0, 0, 0);
        __syncthreads();
    }

    // ---- epilogue: C/D layout col=lane&15, row=quad*4+reg ----
#pragma unroll
    for (int ni = 0; ni < 2; ni++) {
        const int col = colBase + waveC + ni * 16 + lrow;
        const float bv = bias[col];
#pragma unroll
        for (int mi = 0; mi < 4; mi++) {
            const int row0 = rowBase + waveR + mi * 16 + quad * 4;
            float4v v = acc[mi][ni];
#pragma unroll
            for (int i = 0; i < 4; i++)
                out[(long long)(row0 + i) * N_DIM + col] = v[i] + bv;
        }
    }
}

// ---------------- fallback (ws too small): fp32 naive ----------------
__global__ void __launch_bounds__(256) linear_naive(const float* __restrict__ x,
                                                    const float* __restrict__ w,
                                                    const float* __restrict__ bias,
                                                    float* __restrict__ out) {
    __shared__ float xs[K_DIM];
    const int b = blockIdx.y;
    const int o = blockIdx.x * 256 + threadIdx.x;
    for (int k = threadIdx.x; k < K_DIM; k += 256)
        xs[k] = x[(long long)b * K_DIM + k];
    __syncthreads();
    const float4v* wr = (const float4v*)(w + (long long)o * K_DIM);
    float s = 0.f;
    for (int k4 = 0; k4 < K_DIM / 4; k4++) {
        float4v wv = wr[k4];
        float4v xv = *(const float4v*)&xs[k4 * 4];
        s += xv[0] * wv[0] + xv[1] * wv[1] + xv[2] * wv[2] + xv[3] * wv[3];
    }
    out[(long long)b * N_DIM + o] = s + bias[o];
}

extern "C" void kernel_launch(void* const* d_in, const int* in_sizes, int n_in,
                              void* d_out, int out_size, void* d_ws, size_t ws_size,
                              hipStream_t stream) {
    const float* x    = (const float*)d_in[0];   // [4096, 2048]
    const float* w    = (const float*)d_in[1];   // [2048, 2048]
    const float* bias = (const float*)d_in[2];   // [2048]
    float* out = (float*)d_out;                  // [4096, 2048]

    const size_t xElems = (size_t)M_DIM * K_DIM;   // 8388608
    const size_t wElems = (size_t)N_DIM * K_DIM;   // 4194304
    const size_t need = (xElems + wElems) * sizeof(ushort_t);  // ~25.2 MB

    if (ws_size >= need) {
        ushort_t* xb = (ushort_t*)d_ws;
        ushort_t* wb = xb + xElems;
        const int xN8 = (int)(xElems / 8);
        const int totN8 = (int)((xElems + wElems) / 8);
        cvt_both<<<(totN8 + 255) / 256, 256, 0, stream>>>(x, w, (ushort8*)d_ws, xN8, totN8);
        gemm_bf16<<<(M_DIM / 128) * (N_DIM / 128), 512, 0, stream>>>(xb, wb, bias, out);
    } else {
        dim3 grid(N_DIM / 256, M_DIM);
        linear_naive<<<grid, 256, 0, stream>>>(x, w, bias, out);
    }
}

// Round 3
// 132.976 us; speedup vs baseline: 1.0824x; 1.0453x over previous
//
#include <hip/hip_runtime.h>
#include <hip/hip_bf16.h>

// out[b,o] = sum_i x[b,i]*w[o,i] + bias[o]; M=4096, N=2048, K=2048, fp32 io.
// R3: BK 32 -> 64. R2 analysis: each K-iter costs ~1950 cyc of which ~900 is
// the vmcnt(0) barrier drain (HBM-latency of the last staging load) — a
// per-iteration LATENCY cost. Halving iteration count (64->32) amortizes it
// over 2x MFMA work. LDS 32 KB/block (2 resident blocks = 64/160 KB).
// Swizzle for 128B rows: chunk at position p of row r holds global chunk
// p ^ (r&7); staging lane L (-> row L>>3, pos L&7) fetches chunk (L&7)^(L>>3).

#define M_DIM 4096
#define N_DIM 2048
#define K_DIM 2048
#define BK 64

typedef unsigned short ushort_t;
typedef __attribute__((ext_vector_type(8))) short short8;      // 8 bf16 (A/B frag)
typedef __attribute__((ext_vector_type(4))) float float4v;     // C/D frag
typedef __attribute__((ext_vector_type(8))) unsigned short ushort8;

// ---------------- fp32 -> bf16 (RNE), x and w fused in one launch ----------------
__device__ __forceinline__ unsigned short f2bf_rne(float f) {
    unsigned int u = __builtin_bit_cast(unsigned int, f);
    u += 0x7FFFu + ((u >> 16) & 1u);
    return (unsigned short)(u >> 16);
}

__global__ void __launch_bounds__(256) cvt_both(const float* __restrict__ x,
                                                const float* __restrict__ w,
                                                ushort8* __restrict__ ws8,
                                                int xN8, int totN8) {
    int idx = blockIdx.x * 256 + threadIdx.x;
    if (idx >= totN8) return;
    const float4v* in4 = (idx < xN8) ? (const float4v*)x + (size_t)idx * 2
                                     : (const float4v*)w + (size_t)(idx - xN8) * 2;
    float4v a = in4[0];
    float4v b = in4[1];
    ushort8 r;
    r[0] = f2bf_rne(a[0]); r[1] = f2bf_rne(a[1]);
    r[2] = f2bf_rne(a[2]); r[3] = f2bf_rne(a[3]);
    r[4] = f2bf_rne(b[0]); r[5] = f2bf_rne(b[1]);
    r[6] = f2bf_rne(b[2]); r[7] = f2bf_rne(b[3]);
    ws8[idx] = r;
}

// ---------------- async global -> LDS (16B per lane; dest = base + lane*16) ----
__device__ __forceinline__ void async_load16(const void* g, void* l) {
    __builtin_amdgcn_global_load_lds(
        (const __attribute__((address_space(1))) void*)(g),
        (__attribute__((address_space(3))) void*)(l), 16, 0, 0);
}

// ---------------- bf16 MFMA GEMM, C = Xb * Wb^T + bias ----------------
// Xb: [M,K] bf16 row-major, Wb: [N,K] bf16 row-major.
// Block: 128x128 tile, 512 threads = 8 waves in 2(row) x 4(col); wave-tile 64x32.
__global__ void __launch_bounds__(512) gemm_bf16(const ushort_t* __restrict__ xb,
                                                 const ushort_t* __restrict__ wb,
                                                 const float* __restrict__ bias,
                                                 float* __restrict__ out) {
    __shared__ ushort_t ldsA[128 * BK];   // 16 KB
    __shared__ ushort_t ldsB[128 * BK];   // 16 KB

    const int tid  = threadIdx.x;
    const int wave = tid >> 6;
    const int lane = tid & 63;
    const int quad = lane >> 4;    // 0..3
    const int lrow = lane & 15;    // 0..15

    const int bm = blockIdx.x >> 4;    // 0..31
    const int bn = blockIdx.x & 15;    // 0..15
    const int rowBase = bm * 128;
    const int colBase = bn * 128;

    const int waveR = (wave >> 2) * 64;   // 0 or 64
    const int waveC = (wave & 3) * 32;    // 0,32,64,96

    // ---- staging: waves 0-3 stage A rows sgrp*32..+31, waves 4-7 stage B ----
    // 4 instrs/wave; instr j covers 8 rows (64 lanes x 16B / 128B rows).
    // Lane L -> row (L>>3), stored position (L&7); fetch global chunk
    // q = (L&7) ^ (L>>3)  => stored chunk at position p of row r is p^(r&7).
    const int  sgrp = wave & 3;
    const bool isB  = wave >= 4;
    const int  R0   = sgrp * 32;
    const int  q    = (lane & 7) ^ (lane >> 3);
    const ushort_t* src = isB ? wb + (long long)colBase * K_DIM
                              : xb + (long long)rowBase * K_DIM;
    const ushort_t* g0 = src + (long long)(R0 + (lane >> 3)) * K_DIM + q * 8;
    const ushort_t* g1 = g0 + (long long)8  * K_DIM;
    const ushort_t* g2 = g0 + (long long)16 * K_DIM;
    const ushort_t* g3 = g0 + (long long)24 * K_DIM;
    ushort_t* lbase = (isB ? ldsB : ldsA) + R0 * BK;  // wave-uniform
    ushort_t* l0 = lbase;
    ushort_t* l1 = lbase + 8  * BK;
    ushort_t* l2 = lbase + 16 * BK;
    ushort_t* l3 = lbase + 24 * BK;

    // ---- fragment read offsets ----
    // Row r = waveR/C + mi*16 + lrow; chunk c (k-half 0: c=quad, half 1: c=quad+4)
    // stored at position c ^ (r&7) = c ^ (lrow&7). (quad+4)^s = (quad^s)^4.
    const int sw0 = ((quad ^ (lrow & 7))) * 8;      // ushort offset, k-half 0
    const ushort_t* aP = &ldsA[(waveR + lrow) * BK];
    const ushort_t* bP = &ldsB[(waveC + lrow) * BK];

    float4v acc[4][2] = {};

    for (int k0 = 0; k0 < K_DIM; k0 += BK) {
        async_load16(g0, l0);
        async_load16(g1, l1);
        async_load16(g2, l2);
        async_load16(g3, l3);
        g0 += BK; g1 += BK; g2 += BK; g3 += BK;
        __syncthreads();

        short8 af0[4], af1[4], bf0[2], bf1[2];
#pragma unroll
        for (int mi = 0; mi < 4; mi++) {
            af0[mi] = *(const short8*)(aP + mi * 16 * BK + sw0);
            af1[mi] = *(const short8*)(aP + mi * 16 * BK + (sw0 ^ 32));
        }
#pragma unroll
        for (int ni = 0; ni < 2; ni++) {
            bf0[ni] = *(const short8*)(bP + ni * 16 * BK + sw0);
            bf1[ni] = *(const short8*)(bP + ni * 16 * BK + (sw0 ^ 32));
        }
#pragma unroll
        for (int mi = 0; mi < 4; mi++)
#pragma unroll
            for (int ni = 0; ni < 2; ni++)
                acc[mi][ni] = __builtin_amdgcn_mfma_f32_16x16x32_bf16(
                    af0[mi], bf0[ni], acc[mi][ni], 0, 0, 0);
#pragma unroll
        for (int mi = 0; mi < 4; mi++)
#pragma unroll
            for (int ni = 0; ni < 2; ni++)
                acc[mi][ni] = __builtin_amdgcn_mfma_f32_16x16x32_bf16(
                    af1[mi], bf1[ni], acc[mi][ni], 0, 0, 0);
        __syncthreads();
    }

    // ---- epilogue: C/D layout col=lane&15, row=quad*4+reg ----
#pragma unroll
    for (int ni = 0; ni < 2; ni++) {
        const int col = colBase + waveC + ni * 16 + lrow;
        const float bv = bias[col];
#pragma unroll
        for (int mi = 0; mi < 4; mi++) {
            const int row0 = rowBase + waveR + mi * 16 + quad * 4;
            float4v v = acc[mi][ni];
#pragma unroll
            for (int i = 0; i < 4; i++)
                out[(long long)(row0 + i) * N_DIM + col] = v[i] + bv;
        }
    }
}

// ---------------- fallback (ws too small): fp32 naive ----------------
__global__ void __launch_bounds__(256) linear_naive(const float* __restrict__ x,
                                                    const float* __restrict__ w,
                                                    const float* __restrict__ bias,
                                                    float* __restrict__ out) {
    __shared__ float xs[K_DIM];
    const int b = blockIdx.y;
    const int o = blockIdx.x * 256 + threadIdx.x;
    for (int k = threadIdx.x; k < K_DIM; k += 256)
        xs[k] = x[(long long)b * K_DIM + k];
    __syncthreads();
    const float4v* wr = (const float4v*)(w + (long long)o * K_DIM);
    float s = 0.f;
    for (int k4 = 0; k4 < K_DIM / 4; k4++) {
        float4v wv = wr[k4];
        float4v xv = *(const float4v*)&xs[k4 * 4];
        s += xv[0] * wv[0] + xv[1] * wv[1] + xv[2] * wv[2] + xv[3] * wv[3];
    }
    out[(long long)b * N_DIM + o] = s + bias[o];
}

extern "C" void kernel_launch(void* const* d_in, const int* in_sizes, int n_in,
                              void* d_out, int out_size, void* d_ws, size_t ws_size,
                              hipStream_t stream) {
    const float* x    = (const float*)d_in[0];   // [4096, 2048]
    const float* w    = (const float*)d_in[1];   // [2048, 2048]
    const float* bias = (const float*)d_in[2];   // [2048]
    float* out = (float*)d_out;                  // [4096, 2048]

    const size_t xElems = (size_t)M_DIM * K_DIM;   // 8388608
    const size_t wElems = (size_t)N_DIM * K_DIM;   // 4194304
    const size_t need = (xElems + wElems) * sizeof(ushort_t);  // ~25.2 MB

    if (ws_size >= need) {
        ushort_t* xb = (ushort_t*)d_ws;
        ushort_t* wb = xb + xElems;
        const int xN8 = (int)(xElems / 8);
        const int totN8 = (int)((xElems + wElems) / 8);
        cvt_both<<<(totN8 + 255) / 256, 256, 0, stream>>>(x, w, (ushort8*)d_ws, xN8, totN8);
        gemm_bf16<<<(M_DIM / 128) * (N_DIM / 128), 512, 0, stream>>>(xb, wb, bias, out);
    } else {
        dim3 grid(N_DIM / 256, M_DIM);
        linear_naive<<<grid, 256, 0, stream>>>(x, w, bias, out);
    }
}